// Round 5
// baseline (1236.439 us; speedup 1.0000x reference)
//
#include <hip/hip_runtime.h>
#include <math.h>
#include <stdint.h>

#define TOKENS 32768
#define DM 2048
#define DH 1024
#define NE 16
#define BM 128
#define BN 512
#define NPASS 2
#define NSTAGE 64          // DM / 32
#define TAU 5e-4f

// output layout (floats): gates[T*2] | indices[T*2] | probs[T*16]
#define OFF_IDX  (TOKENS * 2)
#define OFF_PROB (TOKENS * 4)

// ws layout (bytes): [0] cnt | [1024] list (32768 int) | [132096] wt (8 MB, optional)
#define WS_LIST 1024
#define WS_WT   132096
#define WS_NEEDED ((size_t)WS_WT + (size_t)64 * 1024 * 64 * 2 * 2)  // + 8388608

typedef short  bf16x8 __attribute__((ext_vector_type(8)));
typedef float  f32x16 __attribute__((ext_vector_type(16)));

// truncation split: hi = top-16-bit bf16 of f; lo = top-16-bit bf16 of (f - hi).

// ---------------- prep: W1 [2048][1024] fp32 -> wt, the exact swizzled LDS image ----------------
// wt[(s*1024 + n)*64 + slot*8 + j]: slot (c ^ (n&7)) holds chunk c;
// chunk c<4 = hi of k [s*32 + c*8 ..+7], c>=4 = lo of k [(c-4)*8 ..].
__global__ __launch_bounds__(256)
void prep_w(const float* __restrict__ W1, short* __restrict__ wt) {
    int gid = blockIdx.x * 256 + threadIdx.x;   // 65536 = 64 s x 1024 n
    int n = gid & 1023;
    int s = gid >> 10;
    float f[32];
    #pragma unroll
    for (int kk = 0; kk < 32; ++kk)
        f[kk] = W1[(size_t)(s * 32 + kk) * DH + n];
    short* rowp = wt + (size_t)gid * 64;
    const int sig = n & 7;
    #pragma unroll
    for (int c = 0; c < 4; ++c) {
        uint32_t hd[4], ld_[4];
        #pragma unroll
        for (int q = 0; q < 4; ++q) {
            uint32_t u0 = __float_as_uint(f[c * 8 + 2 * q]);
            uint32_t u1 = __float_as_uint(f[c * 8 + 2 * q + 1]);
            hd[q] = (u0 >> 16) | (u1 & 0xFFFF0000u);
            float r0 = f[c * 8 + 2 * q]     - __uint_as_float(u0 & 0xFFFF0000u);
            float r1 = f[c * 8 + 2 * q + 1] - __uint_as_float(u1 & 0xFFFF0000u);
            ld_[q] = (__float_as_uint(r0) >> 16) | (__float_as_uint(r1) & 0xFFFF0000u);
        }
        *(int4*)(rowp + ((c ^ sig) << 3))       = make_int4(hd[0], hd[1], hd[2], hd[3]);
        *(int4*)(rowp + (((c + 4) ^ sig) << 3)) = make_int4(ld_[0], ld_[1], ld_[2], ld_[3]);
    }
}

// ---------------- fused GEMM1(MFMA bf16-split) + GEMM2 + softmax + top2 + flag ----------------
// MODE 0: on-the-fly W1 split (proven R4 path, fallback). MODE 1: precomputed wt + T14 pipeline.
template<int MODE>
__global__ __launch_bounds__(512, 2)
void router_mfma(const float* __restrict__ x, const float* __restrict__ W1,
                 const short* __restrict__ wt,
                 const float* __restrict__ b1, const float* __restrict__ W2,
                 const float* __restrict__ b2, float* __restrict__ out,
                 int* __restrict__ cnt, int* __restrict__ list)
{
    __shared__ short xs[BM * 64];        // 16 KB: A tile, XOR-swizzled slots
    __shared__ short bs[BN * 64];        // 64 KB: B tile, XOR-swizzled slots
    __shared__ float w2t[NE * 128];      // 8 KB
    __shared__ float ls[BM * 17];        // padded logits

    float* h_lds = (float*)bs;           // [128][128], reused
    float* lsred = (float*)bs;           // [2048][4], reused

    const int tid  = threadIdx.x;
    const int wid  = tid >> 6;
    const int lane = tid & 63;
    const int l31  = lane & 31;
    const int lh   = lane >> 5;
    const int sg   = lane & 7;
    const int wm   = wid >> 2;
    const int wn   = wid & 3;
    const int m0   = blockIdx.x * BM;

    const int tq  = tid & 31;
    const int egq = (tid >> 5) & 3;
    const int ns  = tid >> 7;

    float lacc[4][4];
    #pragma unroll
    for (int i = 0; i < 4; ++i)
        #pragma unroll
        for (int e = 0; e < 4; ++e) lacc[i][e] = 0.f;

    const int arow = tid >> 2, kq = tid & 3;     // A staging assignment
    const int asig = arow & 7;
    const int nloc = (wid << 6) + lane;          // MODE0 B staging row
    const int sgl  = lane & 7;

    for (int p = 0; p < NPASS; ++p) {
        f32x16 acc[2][4];
        #pragma unroll
        for (int mf = 0; mf < 2; ++mf)
            #pragma unroll
            for (int nf = 0; nf < 4; ++nf)
                #pragma unroll
                for (int q = 0; q < 16; ++q) acc[mf][nf][q] = 0.f;

        int4   breg[8];                  // MODE1 prefetch registers
        uint32_t xhi[4], xlo[4];

        if constexpr (MODE == 1) {
            // ---- cold stage s=0: load + convert, sync (bs free), write ----
            {
                const int4* gsrc = (const int4*)(wt + ((size_t)0 * 1024 + p * BN) * 64
                                                 + wid * 4096 + lane * 8);
                #pragma unroll
                for (int i = 0; i < 8; ++i) breg[i] = gsrc[i * 64];
                const float* xp = x + (size_t)(m0 + arow) * DM + 0 * 32 + kq * 8;
                float4 v0 = *(const float4*)xp;
                float4 v1 = *(const float4*)(xp + 4);
                float f[8] = {v0.x, v0.y, v0.z, v0.w, v1.x, v1.y, v1.z, v1.w};
                #pragma unroll
                for (int q = 0; q < 4; ++q) {
                    uint32_t u0 = __float_as_uint(f[2 * q]);
                    uint32_t u1 = __float_as_uint(f[2 * q + 1]);
                    xhi[q] = (u0 >> 16) | (u1 & 0xFFFF0000u);
                    float r0 = f[2 * q]     - __uint_as_float(u0 & 0xFFFF0000u);
                    float r1 = f[2 * q + 1] - __uint_as_float(u1 & 0xFFFF0000u);
                    xlo[q] = (__float_as_uint(r0) >> 16) | (__float_as_uint(r1) & 0xFFFF0000u);
                }
            }
            __syncthreads();             // previous readers of bs/xs done
            {
                int4* ldst = (int4*)(bs + wid * 4096 + lane * 8);
                #pragma unroll
                for (int i = 0; i < 8; ++i) ldst[i * 64] = breg[i];
                short* ra = xs + arow * 64;
                *(int4*)(ra + ((kq ^ asig) << 3))       = make_int4(xhi[0], xhi[1], xhi[2], xhi[3]);
                *(int4*)(ra + (((4 + kq) ^ asig) << 3)) = make_int4(xlo[0], xlo[1], xlo[2], xlo[3]);
            }
        }

        for (int s = 0; s < NSTAGE; ++s) {
            __syncthreads();   // stage s LDS visible (MODE1) / xs-bs free (MODE0)

            if constexpr (MODE == 0) {
                // ---- B stage: W1 fp32 -> bf16 hi/lo splits, on the fly ----
                {
                    const float* wp = W1 + (size_t)(s * 32) * DH + p * BN + nloc;
                    short* rb = bs + nloc * 64;
                    #pragma unroll
                    for (int h = 0; h < 2; ++h) {
                        float f[16];
                        #pragma unroll
                        for (int j = 0; j < 16; ++j)
                            f[j] = wp[(size_t)(h * 16 + j) * DH];
                        uint32_t hd[8], ld_[8];
                        #pragma unroll
                        for (int q = 0; q < 8; ++q) {
                            uint32_t u0 = __float_as_uint(f[2 * q]);
                            uint32_t u1 = __float_as_uint(f[2 * q + 1]);
                            hd[q] = (u0 >> 16) | (u1 & 0xFFFF0000u);
                            float r0 = f[2 * q]     - __uint_as_float(u0 & 0xFFFF0000u);
                            float r1 = f[2 * q + 1] - __uint_as_float(u1 & 0xFFFF0000u);
                            ld_[q] = (__float_as_uint(r0) >> 16) | (__float_as_uint(r1) & 0xFFFF0000u);
                        }
                        *(int4*)(rb + (((2 * h + 0) ^ sgl) << 3)) = make_int4(hd[0], hd[1], hd[2], hd[3]);
                        *(int4*)(rb + (((2 * h + 1) ^ sgl) << 3)) = make_int4(hd[4], hd[5], hd[6], hd[7]);
                        *(int4*)(rb + (((4 + 2 * h + 0) ^ sgl) << 3)) = make_int4(ld_[0], ld_[1], ld_[2], ld_[3]);
                        *(int4*)(rb + (((4 + 2 * h + 1) ^ sgl) << 3)) = make_int4(ld_[4], ld_[5], ld_[6], ld_[7]);
                    }
                }
                // ---- A stage ----
                {
                    const float* xp = x + (size_t)(m0 + arow) * DM + s * 32 + kq * 8;
                    float4 v0 = *(const float4*)xp;
                    float4 v1 = *(const float4*)(xp + 4);
                    float f[8] = {v0.x, v0.y, v0.z, v0.w, v1.x, v1.y, v1.z, v1.w};
                    uint32_t hd[4], ld_[4];
                    #pragma unroll
                    for (int q = 0; q < 4; ++q) {
                        uint32_t u0 = __float_as_uint(f[2 * q]);
                        uint32_t u1 = __float_as_uint(f[2 * q + 1]);
                        hd[q] = (u0 >> 16) | (u1 & 0xFFFF0000u);
                        float r0 = f[2 * q]     - __uint_as_float(u0 & 0xFFFF0000u);
                        float r1 = f[2 * q + 1] - __uint_as_float(u1 & 0xFFFF0000u);
                        ld_[q] = (__float_as_uint(r0) >> 16) | (__float_as_uint(r1) & 0xFFFF0000u);
                    }
                    short* ra = xs + arow * 64;
                    *(int4*)(ra + ((kq ^ asig) << 3))       = make_int4(hd[0], hd[1], hd[2], hd[3]);
                    *(int4*)(ra + (((4 + kq) ^ asig) << 3)) = make_int4(ld_[0], ld_[1], ld_[2], ld_[3]);
                }
                __syncthreads();
            } else {
                // ---- T14 issue-early: loads for s+1 ----
                if (s < NSTAGE - 1) {
                    const int4* gsrc = (const int4*)(wt + ((size_t)(s + 1) * 1024 + p * BN) * 64
                                                     + wid * 4096 + lane * 8);
                    #pragma unroll
                    for (int i = 0; i < 8; ++i) breg[i] = gsrc[i * 64];
                }
            }

            // ---- compute stage s: 2 ksteps x {x0w0, x0w1, x1w0} ----
            #pragma unroll
            for (int ks = 0; ks < 2; ++ks) {
                bf16x8 a0[2], a1[2], b0[4], b1f[4];
                #pragma unroll
                for (int mf = 0; mf < 2; ++mf) {
                    int base = (wm * 64 + mf * 32 + l31) * 64;
                    a0[mf] = *(const bf16x8*)(xs + base + (((ks * 2 + lh)) ^ sg) * 8);
                    a1[mf] = *(const bf16x8*)(xs + base + (((4 + ks * 2 + lh)) ^ sg) * 8);
                }
                #pragma unroll
                for (int nf = 0; nf < 4; ++nf) {
                    int base = (wn * 128 + nf * 32 + l31) * 64;
                    b0[nf]  = *(const bf16x8*)(bs + base + (((ks * 2 + lh)) ^ sg) * 8);
                    b1f[nf] = *(const bf16x8*)(bs + base + (((4 + ks * 2 + lh)) ^ sg) * 8);
                }
                #pragma unroll
                for (int mf = 0; mf < 2; ++mf)
                    #pragma unroll
                    for (int nf = 0; nf < 4; ++nf) {
                        acc[mf][nf] = __builtin_amdgcn_mfma_f32_32x32x16_bf16(a0[mf], b0[nf],  acc[mf][nf], 0, 0, 0);
                        acc[mf][nf] = __builtin_amdgcn_mfma_f32_32x32x16_bf16(a0[mf], b1f[nf], acc[mf][nf], 0, 0, 0);
                        acc[mf][nf] = __builtin_amdgcn_mfma_f32_32x32x16_bf16(a1[mf], b0[nf],  acc[mf][nf], 0, 0, 0);
                    }
            }

            if constexpr (MODE == 1) {
                // x load + convert for s+1 (overlaps MFMA; vmcnt waits here, not in stage)
                if (s < NSTAGE - 1) {
                    const float* xp = x + (size_t)(m0 + arow) * DM + (s + 1) * 32 + kq * 8;
                    float4 v0 = *(const float4*)xp;
                    float4 v1 = *(const float4*)(xp + 4);
                    float f[8] = {v0.x, v0.y, v0.z, v0.w, v1.x, v1.y, v1.z, v1.w};
                    #pragma unroll
                    for (int q = 0; q < 4; ++q) {
                        uint32_t u0 = __float_as_uint(f[2 * q]);
                        uint32_t u1 = __float_as_uint(f[2 * q + 1]);
                        xhi[q] = (u0 >> 16) | (u1 & 0xFFFF0000u);
                        float r0 = f[2 * q]     - __uint_as_float(u0 & 0xFFFF0000u);
                        float r1 = f[2 * q + 1] - __uint_as_float(u1 & 0xFFFF0000u);
                        xlo[q] = (__float_as_uint(r0) >> 16) | (__float_as_uint(r1) & 0xFFFF0000u);
                    }
                }
                __syncthreads();         // compute done, LDS free
                // ---- write-late: stage s+1 into LDS ----
                if (s < NSTAGE - 1) {
                    int4* ldst = (int4*)(bs + wid * 4096 + lane * 8);
                    #pragma unroll
                    for (int i = 0; i < 8; ++i) ldst[i * 64] = breg[i];
                    short* ra = xs + arow * 64;
                    *(int4*)(ra + ((kq ^ asig) << 3))       = make_int4(xhi[0], xhi[1], xhi[2], xhi[3]);
                    *(int4*)(ra + (((4 + kq) ^ asig) << 3)) = make_int4(xlo[0], xlo[1], xlo[2], xlo[3]);
                }
            }
        }

        // ---- pass epilogue: bias+relu -> h chunks, fused GEMM2 (VALU, exact fp32) ----
        for (int ch = 0; ch < 4; ++ch) {
            __syncthreads();
            if (wn == ch) {
                #pragma unroll
                for (int nf = 0; nf < 4; ++nf) {
                    int col = nf * 32 + l31;
                    float bb = b1[p * BN + ch * 128 + col];
                    #pragma unroll
                    for (int mf = 0; mf < 2; ++mf)
                        #pragma unroll
                        for (int r = 0; r < 16; ++r) {
                            int row = wm * 64 + mf * 32 + (r & 3) + 8 * (r >> 2) + 4 * lh;
                            h_lds[row * 128 + col] = fmaxf(acc[mf][nf][r] + bb, 0.f);
                        }
                }
            }
            #pragma unroll
            for (int q = 0; q < 4; ++q) {
                int i = tid * 4 + q;
                int nn = i >> 4, e = i & 15;
                w2t[e * 128 + nn] = W2[(size_t)(p * BN + ch * 128 + nn) * NE + e];
            }
            __syncthreads();
            for (int nn = 0; nn < 32; ++nn) {
                int nL = ns * 32 + ((nn + tq) & 31);
                float hv[4], wv[4];
                #pragma unroll
                for (int i = 0; i < 4; ++i) hv[i] = h_lds[(tq * 4 + i) * 128 + nL];
                #pragma unroll
                for (int e = 0; e < 4; ++e) wv[e] = w2t[(egq * 4 + e) * 128 + nL];
                #pragma unroll
                for (int i = 0; i < 4; ++i)
                    #pragma unroll
                    for (int e = 0; e < 4; ++e)
                        lacc[i][e] = fmaf(hv[i], wv[e], lacc[i][e]);
            }
        }
    }

    // ---- reduce partial logits over ns slices ----
    __syncthreads();
    #pragma unroll
    for (int i = 0; i < 4; ++i)
        #pragma unroll
        for (int e = 0; e < 4; ++e)
            lsred[((tq * 4 + i) * 16 + egq * 4 + e) * 4 + ns] = lacc[i][e];
    __syncthreads();
    #pragma unroll
    for (int q = 0; q < 4; ++q) {
        int idx = tid * 4 + q;
        int t = idx >> 4, e = idx & 15;
        ls[t * 17 + e] = lsred[idx * 4 + 0] + lsred[idx * 4 + 1] +
                         lsred[idx * 4 + 2] + lsred[idx * 4 + 3] + b2[e];
    }
    __syncthreads();

    // ---- softmax + top2 + flag ----
    if (tid < BM) {
        int t = tid;
        float l[NE]; float mx = -1e30f;
        #pragma unroll
        for (int e = 0; e < NE; ++e) { l[e] = ls[t * 17 + e]; mx = fmaxf(mx, l[e]); }
        float pb[NE]; float ssum = 0.f;
        #pragma unroll
        for (int e = 0; e < NE; ++e) { pb[e] = expf(l[e] - mx); ssum += pb[e]; }
        float inv = 1.f / ssum;
        #pragma unroll
        for (int e = 0; e < NE; ++e) pb[e] *= inv;

        int i1 = 0; float p1 = pb[0];
        #pragma unroll
        for (int e = 1; e < NE; ++e) if (pb[e] > p1) { p1 = pb[e]; i1 = e; }
        int i2 = -1; float p2 = -1.f;
        #pragma unroll
        for (int e = 0; e < NE; ++e) if (e != i1 && pb[e] > p2) { p2 = pb[e]; i2 = e; }
        float p3 = -1.f;
        #pragma unroll
        for (int e = 0; e < NE; ++e) if (e != i1 && e != i2 && pb[e] > p3) p3 = pb[e];

        float denom = p1 + p2 + 1e-8f;
        size_t gt = (size_t)(m0 + t);
        out[gt * 2 + 0] = p1 / denom;
        out[gt * 2 + 1] = p2 / denom;
        out[OFF_IDX + gt * 2 + 0] = (float)i1;
        out[OFF_IDX + gt * 2 + 1] = (float)i2;
        #pragma unroll
        for (int e = 0; e < NE; ++e) out[OFF_PROB + gt * 16 + e] = pb[e];

        if (p1 - p2 < TAU || p2 - p3 < TAU) {
            int k = atomicAdd(cnt, 1);
            list[k] = m0 + t;
        }
    }
}

// ---------------- exact fp32 repair: 4 tokens/block streaming GEMM ----------------
__global__ __launch_bounds__(256, 3)
void repair4(const float* __restrict__ x, const float* __restrict__ W1,
             const float* __restrict__ b1, const float* __restrict__ W2,
             const float* __restrict__ b2, float* __restrict__ out,
             const int* __restrict__ cnt, const int* __restrict__ list)
{
    __shared__ float xsh[4][DM];
    __shared__ float hsh[4][DH];
    __shared__ float red[256];
    __shared__ float lg[4][NE];
    __shared__ int   tokid[4];

    const int tid  = threadIdx.x;
    const int nrep = cnt[0];

    for (int g = blockIdx.x; g * 4 < nrep; g += gridDim.x) {
        __syncthreads();
        if (tid < 4) {
            int j = g * 4 + tid;
            tokid[tid] = list[j < nrep ? j : 0];
        }
        __syncthreads();

        #pragma unroll
        for (int i = 0; i < 8; ++i) {
            int slot = tid + i * 256;
            int t = slot >> 9, c = slot & 511;
            *(float4*)(&xsh[t][c * 4]) =
                *(const float4*)(x + (size_t)tokid[t] * DM + c * 4);
        }
        __syncthreads();

        float acc[4][4];
        #pragma unroll
        for (int t = 0; t < 4; ++t)
            #pragma unroll
            for (int q = 0; q < 4; ++q) acc[t][q] = 0.f;

        for (int k4 = 0; k4 < DM / 4; ++k4) {
            float4 xv[4];
            #pragma unroll
            for (int t = 0; t < 4; ++t)
                xv[t] = *(const float4*)(&xsh[t][k4 * 4]);
            #pragma unroll
            for (int kk = 0; kk < 4; ++kk) {
                const float4 w = *(const float4*)(W1 + (size_t)(k4 * 4 + kk) * DH + tid * 4);
                #pragma unroll
                for (int t = 0; t < 4; ++t) {
                    const float a = ((const float*)&xv[t])[kk];
                    acc[t][0] = fmaf(a, w.x, acc[t][0]);
                    acc[t][1] = fmaf(a, w.y, acc[t][1]);
                    acc[t][2] = fmaf(a, w.z, acc[t][2]);
                    acc[t][3] = fmaf(a, w.w, acc[t][3]);
                }
            }
        }

        {
            const float4 bv = *(const float4*)(b1 + tid * 4);
            #pragma unroll
            for (int t = 0; t < 4; ++t) {
                float4 h;
                h.x = fmaxf(acc[t][0] + bv.x, 0.f);
                h.y = fmaxf(acc[t][1] + bv.y, 0.f);
                h.z = fmaxf(acc[t][2] + bv.z, 0.f);
                h.w = fmaxf(acc[t][3] + bv.w, 0.f);
                *(float4*)(&hsh[t][tid * 4]) = h;
            }
        }
        __syncthreads();

        {
            const int e  = tid & 15;
            const int t  = (tid >> 4) & 3;
            const int sl = tid >> 6;
            float ps = 0.f;
            for (int q = 0; q < 256; ++q) {
                int n = sl * 256 + q;
                ps = fmaf(hsh[t][n], W2[n * NE + e], ps);
            }
            red[tid] = ps;
        }
        __syncthreads();
        if (tid < 64) {
            int t = tid >> 4, e = tid & 15;
            lg[t][e] = b2[e] + red[0 * 64 + t * 16 + e] + red[1 * 64 + t * 16 + e]
                             + red[2 * 64 + t * 16 + e] + red[3 * 64 + t * 16 + e];
        }
        __syncthreads();

        if (tid < 4 && g * 4 + tid < nrep) {
            const int t = tid;
            float l[NE]; float mx = -1e30f;
            #pragma unroll
            for (int e = 0; e < NE; ++e) { l[e] = lg[t][e]; mx = fmaxf(mx, l[e]); }
            float pb[NE]; float ssum = 0.f;
            #pragma unroll
            for (int e = 0; e < NE; ++e) { pb[e] = expf(l[e] - mx); ssum += pb[e]; }
            float inv = 1.f / ssum;
            #pragma unroll
            for (int e = 0; e < NE; ++e) pb[e] *= inv;

            int i1 = 0; float p1 = pb[0];
            #pragma unroll
            for (int e = 1; e < NE; ++e) if (pb[e] > p1) { p1 = pb[e]; i1 = e; }
            int i2 = -1; float p2 = -1.f;
            #pragma unroll
            for (int e = 0; e < NE; ++e) if (e != i1 && pb[e] > p2) { p2 = pb[e]; i2 = e; }
            float denom = p1 + p2 + 1e-8f;
            size_t gt = (size_t)tokid[t];
            out[gt * 2 + 0] = p1 / denom;
            out[gt * 2 + 1] = p2 / denom;
            out[OFF_IDX + gt * 2 + 0] = (float)i1;
            out[OFF_IDX + gt * 2 + 1] = (float)i2;
            #pragma unroll
            for (int e = 0; e < NE; ++e) out[OFF_PROB + gt * 16 + e] = pb[e];
        }
    }
}

extern "C" void kernel_launch(void* const* d_in, const int* in_sizes, int n_in,
                              void* d_out, int out_size, void* d_ws, size_t ws_size,
                              hipStream_t stream) {
    const float* x  = (const float*)d_in[0];
    const float* W1 = (const float*)d_in[1];
    const float* b1 = (const float*)d_in[2];
    const float* W2 = (const float*)d_in[3];
    const float* b2 = (const float*)d_in[4];
    float* out = (float*)d_out;

    int*   cnt  = (int*)d_ws;
    int*   list = (int*)((char*)d_ws + WS_LIST);
    short* wt   = (short*)((char*)d_ws + WS_WT);

    hipMemsetAsync(cnt, 0, sizeof(int), stream);
    if (ws_size >= WS_NEEDED) {
        hipLaunchKernelGGL(prep_w, dim3(256), dim3(256), 0, stream, W1, wt);
        hipLaunchKernelGGL((router_mfma<1>), dim3(TOKENS / BM), dim3(512), 0, stream,
                           x, W1, wt, b1, W2, b2, out, cnt, list);
    } else {
        hipLaunchKernelGGL((router_mfma<0>), dim3(TOKENS / BM), dim3(512), 0, stream,
                           x, W1, wt, b1, W2, b2, out, cnt, list);
    }
    hipLaunchKernelGGL(repair4, dim3(512), dim3(256), 0, stream,
                       x, W1, b1, W2, b2, out, cnt, list);
}